// Round 5
// baseline (218.749 us; speedup 1.0000x reference)
//
#include <hip/hip_runtime.h>

// Problem constants (match reference)
#define BB 8
#define CC 3
#define HH 1024
#define WW 1024
#define NS 15728   // int(1024*1024*0.015)

// Gaussian 5-tap, sigma=1.5, normalized
#define G0 0.1200784f
#define G1 0.2338808f
#define G2 0.2920816f

// ---------------------------------------------------------------------------
// Kernel 1: scatter snow boxes into a per-batch bitmask (1 bit / pixel).
// mbits layout: [B][H][W/32] uint32 -> 32 words per image row.
// ---------------------------------------------------------------------------
__global__ __launch_bounds__(256) void snow_mask_kernel(
    const int* __restrict__ ys, const int* __restrict__ xs,
    const int* __restrict__ rs, unsigned int* __restrict__ mbits) {
  int s = blockIdx.x * 256 + threadIdx.x;
  if (s >= NS) return;
  int b = blockIdx.y;
  int idx = b * NS + s;
  int y = ys[idx];
  int x = xs[idx];
  int r = rs[idx] + 1;  // radius in {1,2,3}
  int x0 = max(x - r, 0), x1 = min(x + r, WW - 1);
  int y0 = max(y - r, 0), y1 = min(y + r, HH - 1);
  int w0 = x0 >> 5, w1 = x1 >> 5;
  unsigned int m0 = 0xFFFFFFFFu << (x0 & 31);
  unsigned int m1 = 0xFFFFFFFFu >> (31 - (x1 & 31));
  for (int py = y0; py <= y1; ++py) {
    unsigned int* rowp = mbits + ((unsigned)(b * HH + py) << 5);
    if (w0 == w1) {
      atomicOr(&rowp[w0], m0 & m1);
    } else {
      atomicOr(&rowp[w0], m0);
      atomicOr(&rowp[w1], m1);
    }
  }
}

// ---------------------------------------------------------------------------
// Kernel 2: masked-fill + separable 5x5 Gaussian + clip — BARRIER-FREE stream.
// Block = full-width 32-row strip of one (b,c); 256 threads; thread t owns
// cols 4t..4t+3. Vertical 5-tap = register sliding window over streamed rows;
// horizontal halo via two extra 8B loads per row (L1 hits, no LDS/shuffles).
// No __syncthreads -> loads/compute/stores of consecutive rows overlap freely.
// ---------------------------------------------------------------------------
#define STRIP 32

struct Row {
  float4 v;        // cols c..c+3
  float2 lh, rh;   // cols c-2,c-1 and c+4,c+5
  unsigned int m0, m1;  // mask words covering bits for cols c-2..c+5
};

__device__ __forceinline__ Row load_row(const float* __restrict__ xrow,
                                        const unsigned int* __restrict__ mrow,
                                        int off_v, int off_l, int off_r,
                                        int iw0, int iw1) {
  Row rd;
  rd.v = *(const float4*)(xrow + off_v);
  rd.lh = *(const float2*)(xrow + off_l);
  rd.rh = *(const float2*)(xrow + off_r);
  rd.m0 = mrow[iw0];
  rd.m1 = mrow[iw1];
  return rd;
}

__device__ __forceinline__ float4 hpass(Row rd, int bitpos,
                                        bool l_edge, bool r_edge, bool valid) {
  unsigned long long mm =
      (unsigned long long)rd.m0 | ((unsigned long long)rd.m1 << 32);
  unsigned int bits = (unsigned int)(mm >> bitpos);  // bit k <-> col c-2+k
  float4 v = rd.v;
  float2 lh = rd.lh, rh = rd.rh;
  if (bits & 1u)   lh.x = 0.95f;
  if (bits & 2u)   lh.y = 0.95f;
  if (bits & 4u)   v.x = 0.95f;
  if (bits & 8u)   v.y = 0.95f;
  if (bits & 16u)  v.z = 0.95f;
  if (bits & 32u)  v.w = 0.95f;
  if (bits & 64u)  rh.x = 0.95f;
  if (bits & 128u) rh.y = 0.95f;
  if (l_edge) { lh.x = 0.f; lh.y = 0.f; }   // cols -2,-1 -> zero pad
  if (r_edge) { rh.x = 0.f; rh.y = 0.f; }   // cols 1024,1025 -> zero pad
  float4 h;
  h.x = G0 * (lh.x + v.z) + G1 * (lh.y + v.y) + G2 * v.x;
  h.y = G0 * (lh.y + v.w) + G1 * (v.x + v.z) + G2 * v.y;
  h.z = G0 * (v.x + rh.x) + G1 * (v.y + v.w) + G2 * v.z;
  h.w = G0 * (v.y + rh.y) + G1 * (v.z + rh.x) + G2 * v.w;
  if (!valid) { h.x = 0.f; h.y = 0.f; h.z = 0.f; h.w = 0.f; }  // row zero pad
  return h;
}

__global__ __launch_bounds__(256, 4) void snow_blur_kernel(
    const float* __restrict__ x, const unsigned int* __restrict__ mbits,
    float* __restrict__ out) {
  const int bz = blockIdx.y;        // b*CC + c
  const int b = bz / CC;
  const int gy0 = blockIdx.x * STRIP;
  const int t = threadIdx.x;
  const float* __restrict__ xp = x + (size_t)bz * (HH * WW);
  const unsigned int* __restrict__ mb = mbits + ((unsigned)(b * HH) << 5);

  const int c = 4 * t;
  const int off_v = c;
  const int off_l = max(c - 2, 0);        // 8B aligned
  const int off_r = min(c + 4, WW - 2);   // 8B aligned
  const int iw0 = max((c - 2) >> 5, 0);
  const int iw1 = min((c + 4) >> 5, 31);
  const int bitpos = (c - 2) & 31;
  const bool l_edge = (t == 0);
  const bool r_edge = (t == 255);

  float4 h0, h1, h2, h3, h4;
  h0 = h1 = h2 = h3 = make_float4(0.f, 0.f, 0.f, 0.f);
  (void)h0;

  // prime: row index ir = gy0 - 2 + r
  int ir0 = gy0 - 2;
  int g0c = min(max(ir0, 0), HH - 1);
  Row cur = load_row(xp + (size_t)g0c * WW, mb + (g0c << 5),
                     off_v, off_l, off_r, iw0, iw1);

  float* op = out + (size_t)bz * (HH * WW) + (size_t)gy0 * WW + c;

#pragma unroll
  for (int r = 0; r < STRIP + 4; ++r) {
    int ir = gy0 - 2 + r;
    bool valid = (ir >= 0) && (ir < HH);

    Row nxt;
    if (r < STRIP + 3) {  // prefetch next row while computing this one
      int g2 = min(max(ir + 1, 0), HH - 1);
      nxt = load_row(xp + (size_t)g2 * WW, mb + (g2 << 5),
                     off_v, off_l, off_r, iw0, iw1);
    }

    float4 hh = hpass(cur, bitpos, l_edge, r_edge, valid);
    h0 = h1; h1 = h2; h2 = h3; h3 = h4; h4 = hh;

    if (r >= 4) {
      float4 s;
      s.x = G0 * (h0.x + h4.x) + G1 * (h1.x + h3.x) + G2 * h2.x;
      s.y = G0 * (h0.y + h4.y) + G1 * (h1.y + h3.y) + G2 * h2.y;
      s.z = G0 * (h0.z + h4.z) + G1 * (h1.z + h3.z) + G2 * h2.z;
      s.w = G0 * (h0.w + h4.w) + G1 * (h1.w + h3.w) + G2 * h2.w;
      s.x = fminf(fmaxf(s.x, 0.f), 1.f);
      s.y = fminf(fmaxf(s.y, 0.f), 1.f);
      s.z = fminf(fmaxf(s.z, 0.f), 1.f);
      s.w = fminf(fmaxf(s.w, 0.f), 1.f);
      *(float4*)(op + (size_t)(r - 4) * WW) = s;
    }
    cur = nxt;
  }
}

// ---------------------------------------------------------------------------
extern "C" void kernel_launch(void* const* d_in, const int* in_sizes, int n_in,
                              void* d_out, int out_size, void* d_ws, size_t ws_size,
                              hipStream_t stream) {
  const float* x = (const float*)d_in[0];
  const int* ys = (const int*)d_in[1];
  const int* xs = (const int*)d_in[2];
  const int* rs = (const int*)d_in[3];
  float* out = (float*)d_out;

  unsigned int* mbits = (unsigned int*)d_ws;  // B*H*W/8 = 1 MiB
  hipMemsetAsync(mbits, 0, (size_t)BB * HH * WW / 8, stream);

  dim3 mgrid((NS + 255) / 256, BB);
  snow_mask_kernel<<<mgrid, 256, 0, stream>>>(ys, xs, rs, mbits);

  dim3 grid(HH / STRIP, BB * CC);  // 32 strips x 24 images = 768 blocks (3/CU)
  snow_blur_kernel<<<grid, 256, 0, stream>>>(x, mbits, out);
}